// Round 1
// baseline (88.123 us; speedup 1.0000x reference)
//
#include <hip/hip_runtime.h>

#define CHUNK 6

// One thread per 6-element chunk. C = N/6 == M for this problem, but we
// handle the general case by bounds-checking the average streams separately.
__global__ __launch_bounds__(256) void loss_partial_kernel(
    const float* __restrict__ resnet, const float* __restrict__ gru,
    const float* __restrict__ avgp,   const float* __restrict__ y,
    const float* __restrict__ avgh,
    double* __restrict__ acc, int C, int M)
{
    int idx = blockIdx.x * blockDim.x + threadIdx.x;

    float s_l1a = 0.f, s_l1b = 0.f, s_sm = 0.f;
    if (idx < C) {
        // gru chunk: smoothness |x - mean(chunk)|
        const float2* g2 = reinterpret_cast<const float2*>(gru) + 3 * idx;
        float2 ga = g2[0], gb = g2[1], gc = g2[2];
        float m = (ga.x + ga.y + gb.x + gb.y + gc.x + gc.y) * (1.0f / 6.0f);
        s_sm = fabsf(ga.x - m) + fabsf(ga.y - m)
             + fabsf(gb.x - m) + fabsf(gb.y - m)
             + fabsf(gc.x - m) + fabsf(gc.y - m);

        // resnet vs y L1 over the same 6 elements
        const float2* r2 = reinterpret_cast<const float2*>(resnet) + 3 * idx;
        const float2* y2 = reinterpret_cast<const float2*>(y) + 3 * idx;
        float2 ra = r2[0], rb = r2[1], rc = r2[2];
        float2 ya = y2[0], yb = y2[1], yc = y2[2];
        s_l1a = fabsf(ra.x - ya.x) + fabsf(ra.y - ya.y)
              + fabsf(rb.x - yb.x) + fabsf(rb.y - yb.y)
              + fabsf(rc.x - yc.x) + fabsf(rc.y - yc.y);
    }
    if (idx < M) {
        // average streams: one element per thread
        s_l1b = fabsf(avgp[idx] - avgh[idx]);
    }

    // wave-64 shuffle reduction
    #pragma unroll
    for (int off = 32; off > 0; off >>= 1) {
        s_l1a += __shfl_down(s_l1a, off, 64);
        s_l1b += __shfl_down(s_l1b, off, 64);
        s_sm  += __shfl_down(s_sm,  off, 64);
    }

    __shared__ float red0[4], red1[4], red2[4];   // 256 threads = 4 waves
    int wave = threadIdx.x >> 6;
    int lane = threadIdx.x & 63;
    if (lane == 0) { red0[wave] = s_l1a; red1[wave] = s_l1b; red2[wave] = s_sm; }
    __syncthreads();

    if (threadIdx.x == 0) {
        double a = (double)red0[0] + (double)red0[1] + (double)red0[2] + (double)red0[3];
        double b = (double)red1[0] + (double)red1[1] + (double)red1[2] + (double)red1[3];
        double c = (double)red2[0] + (double)red2[1] + (double)red2[2] + (double)red2[3];
        atomicAdd(&acc[0], a);
        atomicAdd(&acc[1], b);
        atomicAdd(&acc[2], c);
    }
}

__global__ void loss_final_kernel(const double* __restrict__ acc,
                                  float* __restrict__ out, int N, int M)
{
    double l1     = acc[0] / (double)N + acc[1] / (double)M;
    double smooth = acc[2] / (double)CHUNK;
    double total  = l1 + 100.0 * smooth;
    out[0] = (float)total;
    out[1] = (float)l1;
    out[2] = (float)smooth;
}

extern "C" void kernel_launch(void* const* d_in, const int* in_sizes, int n_in,
                              void* d_out, int out_size, void* d_ws, size_t ws_size,
                              hipStream_t stream) {
    const float* resnet = (const float*)d_in[0];
    const float* gru    = (const float*)d_in[1];
    const float* avgp   = (const float*)d_in[2];
    const float* y      = (const float*)d_in[3];
    const float* avgh   = (const float*)d_in[4];
    float* out = (float*)d_out;

    int N = in_sizes[0];          // 3,000,000
    int M = in_sizes[2];          // 500,000
    int C = N / CHUNK;            // 500,000 chunks

    double* acc = (double*)d_ws;
    hipMemsetAsync(acc, 0, 3 * sizeof(double), stream);

    int work = (C > M) ? C : M;
    int block = 256;
    int grid = (work + block - 1) / block;
    loss_partial_kernel<<<grid, block, 0, stream>>>(resnet, gru, avgp, y, avgh,
                                                    acc, C, M);
    loss_final_kernel<<<1, 1, 0, stream>>>(acc, out, N, M);
}

// Round 2
// 16.354 us; speedup vs baseline: 5.3883x; 5.3883x over previous
//
#include <hip/hip_runtime.h>

#define CHUNK 6

// Stage 1: one thread per PAIR of 6-chunks (12 floats = 3x float4 per stream)
// plus one PAIR of average-stream elements (float2). Block-level reduction,
// one partial triple per block written to d_ws (SoA: p0[nb], p1[nb], p2[nb]).
// No global atomics (same-address fp64 atomic serialization was 76us in R1).
__global__ __launch_bounds__(256) void loss_partial_kernel(
    const float* __restrict__ resnet, const float* __restrict__ gru,
    const float* __restrict__ avgp,   const float* __restrict__ y,
    const float* __restrict__ avgh,
    float* __restrict__ partials, int nb, int C, int M)
{
    int idx = blockIdx.x * blockDim.x + threadIdx.x;
    int Cp = C >> 1;   // chunk pairs
    int Mp = M >> 1;   // avg element pairs

    float s_l1a = 0.f, s_l1b = 0.f, s_sm = 0.f;

    if (idx < Cp) {
        const float4* g4 = reinterpret_cast<const float4*>(gru) + 3 * idx;
        float4 ga = g4[0], gb = g4[1], gc = g4[2];
        // chunk A = ga.xyzw + gb.xy ; chunk B = gb.zw + gc.xyzw
        float mA = (ga.x + ga.y + ga.z + ga.w + gb.x + gb.y) * (1.0f / 6.0f);
        float mB = (gb.z + gb.w + gc.x + gc.y + gc.z + gc.w) * (1.0f / 6.0f);
        s_sm = fabsf(ga.x - mA) + fabsf(ga.y - mA) + fabsf(ga.z - mA) + fabsf(ga.w - mA)
             + fabsf(gb.x - mA) + fabsf(gb.y - mA)
             + fabsf(gb.z - mB) + fabsf(gb.w - mB)
             + fabsf(gc.x - mB) + fabsf(gc.y - mB) + fabsf(gc.z - mB) + fabsf(gc.w - mB);

        const float4* r4 = reinterpret_cast<const float4*>(resnet) + 3 * idx;
        const float4* y4 = reinterpret_cast<const float4*>(y) + 3 * idx;
        float4 ra = r4[0], rb = r4[1], rc = r4[2];
        float4 ya = y4[0], yb = y4[1], yc = y4[2];
        s_l1a = fabsf(ra.x - ya.x) + fabsf(ra.y - ya.y) + fabsf(ra.z - ya.z) + fabsf(ra.w - ya.w)
              + fabsf(rb.x - yb.x) + fabsf(rb.y - yb.y) + fabsf(rb.z - yb.z) + fabsf(rb.w - yb.w)
              + fabsf(rc.x - yc.x) + fabsf(rc.y - yc.y) + fabsf(rc.z - yc.z) + fabsf(rc.w - yc.w);
    } else if ((C & 1) && idx == Cp) {
        // general-case tail: one leftover chunk (not hit when C even)
        int base = CHUNK * (C - 1);
        float x0 = gru[base+0], x1 = gru[base+1], x2 = gru[base+2];
        float x3 = gru[base+3], x4 = gru[base+4], x5 = gru[base+5];
        float m = (x0 + x1 + x2 + x3 + x4 + x5) * (1.0f / 6.0f);
        s_sm = fabsf(x0-m)+fabsf(x1-m)+fabsf(x2-m)+fabsf(x3-m)+fabsf(x4-m)+fabsf(x5-m);
        for (int k = 0; k < CHUNK; ++k)
            s_l1a += fabsf(resnet[base+k] - y[base+k]);
    }

    if (idx < Mp) {
        const float2* ap2 = reinterpret_cast<const float2*>(avgp) + idx;
        const float2* ah2 = reinterpret_cast<const float2*>(avgh) + idx;
        float2 ap = *ap2, ah = *ah2;
        s_l1b = fabsf(ap.x - ah.x) + fabsf(ap.y - ah.y);
    } else if ((M & 1) && idx == Mp) {
        s_l1b = fabsf(avgp[M-1] - avgh[M-1]);
    }

    // wave-64 shuffle reduction
    #pragma unroll
    for (int off = 32; off > 0; off >>= 1) {
        s_l1a += __shfl_down(s_l1a, off, 64);
        s_l1b += __shfl_down(s_l1b, off, 64);
        s_sm  += __shfl_down(s_sm,  off, 64);
    }

    __shared__ float red0[4], red1[4], red2[4];   // 256 threads = 4 waves
    int wave = threadIdx.x >> 6;
    int lane = threadIdx.x & 63;
    if (lane == 0) { red0[wave] = s_l1a; red1[wave] = s_l1b; red2[wave] = s_sm; }
    __syncthreads();

    if (threadIdx.x == 0) {
        partials[blockIdx.x]          = red0[0] + red0[1] + red0[2] + red0[3];
        partials[nb + blockIdx.x]     = red1[0] + red1[1] + red1[2] + red1[3];
        partials[2 * nb + blockIdx.x] = red2[0] + red2[1] + red2[2] + red2[3];
    }
}

// Stage 2: single block reduces nb partial triples (double accum) + finalizes.
__global__ __launch_bounds__(1024) void loss_reduce_kernel(
    const float* __restrict__ partials, int nb,
    float* __restrict__ out, int N, int M)
{
    double a = 0.0, b = 0.0, c = 0.0;
    for (int i = threadIdx.x; i < nb; i += blockDim.x) {
        a += (double)partials[i];
        b += (double)partials[nb + i];
        c += (double)partials[2 * nb + i];
    }

    #pragma unroll
    for (int off = 32; off > 0; off >>= 1) {
        a += __shfl_down(a, off, 64);
        b += __shfl_down(b, off, 64);
        c += __shfl_down(c, off, 64);
    }

    __shared__ double ra[16], rb[16], rc[16];    // up to 16 waves
    int wave = threadIdx.x >> 6;
    int lane = threadIdx.x & 63;
    int nwaves = (blockDim.x + 63) >> 6;
    if (lane == 0) { ra[wave] = a; rb[wave] = b; rc[wave] = c; }
    __syncthreads();

    if (threadIdx.x == 0) {
        double sa = 0.0, sb = 0.0, sc = 0.0;
        for (int w = 0; w < nwaves; ++w) { sa += ra[w]; sb += rb[w]; sc += rc[w]; }
        double l1     = sa / (double)N + sb / (double)M;
        double smooth = sc / (double)CHUNK;
        double total  = l1 + 100.0 * smooth;
        out[0] = (float)total;
        out[1] = (float)l1;
        out[2] = (float)smooth;
    }
}

extern "C" void kernel_launch(void* const* d_in, const int* in_sizes, int n_in,
                              void* d_out, int out_size, void* d_ws, size_t ws_size,
                              hipStream_t stream) {
    const float* resnet = (const float*)d_in[0];
    const float* gru    = (const float*)d_in[1];
    const float* avgp   = (const float*)d_in[2];
    const float* y      = (const float*)d_in[3];
    const float* avgh   = (const float*)d_in[4];
    float* out = (float*)d_out;

    int N = in_sizes[0];          // 3,000,000
    int M = in_sizes[2];          // 500,000
    int C = N / CHUNK;            // 500,000 chunks

    int Cp = (C >> 1) + (C & 1);
    int Mp = (M >> 1) + (M & 1);
    int work = (Cp > Mp) ? Cp : Mp;
    int block = 256;
    int nb = (work + block - 1) / block;     // ~977 blocks

    float* partials = (float*)d_ws;          // 3 * nb floats

    loss_partial_kernel<<<nb, block, 0, stream>>>(resnet, gru, avgp, y, avgh,
                                                  partials, nb, C, M);
    loss_reduce_kernel<<<1, 1024, 0, stream>>>(partials, nb, out, N, M);
}